// Round 9
// baseline (197.882 us; speedup 1.0000x reference)
//
#include <hip/hip_runtime.h>
#include <math.h>

#define UDIM 256
#define BATCH 64
#define MATN 65536   // 256*256
#define PITCH 280    // LDS row pitch (bf16): 560B = 16B-aligned

typedef __bf16 bf16x8 __attribute__((ext_vector_type(8)));
typedef float  f32x4  __attribute__((ext_vector_type(4)));

__device__ __forceinline__ float softplusf(float x) { return log1pf(expf(x)); }
__device__ __forceinline__ float sigmoidf_(float x) { return 1.f/(1.f+expf(-x)); }

// Fragment-direct layout (verified rounds 4-8): chunk(rt,kt) = rows rt*16..+15
// x k kt*32..+31; lane = (row&15) | ((k>>3)&3)<<4; 8 contiguous bf16 per lane.
__device__ __forceinline__ bf16x8 frag_load(const __bf16* base, int rt, int kt, int lane) {
  return *(const bf16x8*)(base + (((size_t)(rt*8 + kt))*64 + lane)*8);
}

__device__ __forceinline__ bf16x8 cvt8(const float* p) {
  const float4 f0 = *(const float4*)p;
  const float4 f1 = *(const float4*)(p + 4);
  bf16x8 v;
  v[0]=(__bf16)f0.x; v[1]=(__bf16)f0.y; v[2]=(__bf16)f0.z; v[3]=(__bf16)f0.w;
  v[4]=(__bf16)f1.x; v[5]=(__bf16)f1.y; v[6]=(__bf16)f1.z; v[7]=(__bf16)f1.w;
  return v;
}

// ---------------------------------------------------------------------------
// prepk: one launch, 1136 blocks.
//   u < 1024  : S 64x64 tile -> LDS -> emit Sf (fragment-direct bf16) AND
//               Sc (C-linear bf16: slot ((b*16+s)*256+t)*16 + ct*4+v for
//               i = s*16+q*4+v, j = w*64+ct*16+r, t = w*64+q*16+r).
//   1024..1119: fragment-direct bf16 weight transposes (6 matrices x 16 tiles)
//   1120..1135: scalar reductions xx, pp, trS.
// scal: xx[0..63], pp[64..127], trS[128..191], gg[192..255], trG[256..319]
// ---------------------------------------------------------------------------
__global__ __launch_bounds__(256) void prepk(
    const float* __restrict__ S, const float* __restrict__ x,
    const float* __restrict__ prev,
    const float* __restrict__ Uz, const float* __restrict__ Wz,
    const float* __restrict__ Ur, const float* __restrict__ Wr,
    const float* __restrict__ Uh, const float* __restrict__ Wh,
    __bf16* __restrict__ Fu_z, __bf16* __restrict__ Fw_z,
    __bf16* __restrict__ Fu_r, __bf16* __restrict__ Fw_r,
    __bf16* __restrict__ Fu_h, __bf16* __restrict__ Fw_h,
    __bf16* __restrict__ Sf, __bf16* __restrict__ Sc,
    float* __restrict__ scal)
{
  __shared__ float tile[64][65];
  const int u = blockIdx.x;
  const int t = threadIdx.x;

  if (u < 1024) {
    const int bx = u & 3, by = (u >> 2) & 3, b = u >> 4;
    const size_t sb = (size_t)b * MATN;
    const int tx = t & 15, ty = t >> 4;
#pragma unroll
    for (int rr = 0; rr < 4; ++rr) {
      const int row = ty*4 + rr;
      const float4 f = *(const float4*)(S + sb + (size_t)(by*64 + row)*UDIM + bx*64 + tx*4);
      tile[row][tx*4+0] = f.x; tile[row][tx*4+1] = f.y;
      tile[row][tx*4+2] = f.z; tile[row][tx*4+3] = f.w;
    }
    __syncthreads();
    // --- Sf: fragment-direct ---
#pragma unroll
    for (int ss = 0; ss < 2; ++ss) {
      const int s = t + ss*256;
      const int chunk = s >> 6, lane = s & 63;
      const int rt_l = chunk >> 1, kt_l = chunk & 1;
      const int rl = rt_l*16 + (lane & 15), cl = kt_l*32 + (lane >> 4)*8;
      __align__(16) __bf16 tmp[8];
#pragma unroll
      for (int e = 0; e < 8; ++e) tmp[e] = (__bf16)tile[rl][cl + e];
      *(uint4*)(Sf + sb + (((size_t)((by*4 + rt_l)*8 + bx*2 + kt_l))*64 + lane)*8)
          = *(const uint4*)tmp;
    }
    // --- Sc: C-linear (strip sl = t>>6, le = t&63) ---
    {
      const int sl = t >> 6, le = t & 63, q = le >> 4, r = le & 15;
      __align__(16) __bf16 c16[16];
#pragma unroll
      for (int ct = 0; ct < 4; ++ct)
#pragma unroll
        for (int v = 0; v < 4; ++v)
          c16[ct*4 + v] = (__bf16)tile[sl*16 + q*4 + v][ct*16 + r];
      __bf16* dst = Sc + ((size_t)(b*16 + by*4 + sl)*256 + bx*64 + le)*16;
      *(uint4*)dst       = *(const uint4*)&c16[0];
      *(uint4*)(dst + 8) = *(const uint4*)&c16[8];
    }
    return;
  }

  if (u < 1120) {
    const int uu = u - 1024;
    const int mat = uu >> 4, tl = uu & 15;
    const int n0 = (tl & 3)*64, k0 = (tl >> 2)*64;
    const float* W; __bf16* F;
    switch (mat) {
      case 0: W = Uz; F = Fu_z; break;  case 1: W = Wz; F = Fw_z; break;
      case 2: W = Ur; F = Fu_r; break;  case 3: W = Wr; F = Fw_r; break;
      case 4: W = Uh; F = Fu_h; break;  default: W = Wh; F = Fw_h; break;
    }
    const int tx = t & 15, ty = t >> 4;
#pragma unroll
    for (int rr = 0; rr < 4; ++rr) {
      const int row = ty*4 + rr;
      const float4 f = *(const float4*)(W + (size_t)(k0 + row)*UDIM + n0 + tx*4);
      tile[row][tx*4+0] = f.x; tile[row][tx*4+1] = f.y;
      tile[row][tx*4+2] = f.z; tile[row][tx*4+3] = f.w;
    }
    __syncthreads();
#pragma unroll
    for (int ss = 0; ss < 2; ++ss) {
      const int s = t + ss*256;
      const int rt_l = s >> 7, kt_l = (s >> 6) & 1, lane = s & 63;
      const int nl = rt_l*16 + (lane & 15), kb = kt_l*32 + (lane >> 4)*8;
      __align__(16) __bf16 tmp[8];
#pragma unroll
      for (int e = 0; e < 8; ++e) tmp[e] = (__bf16)tile[kb + e][nl];
      *(uint4*)(F + (((size_t)((((n0 >> 4) + rt_l)*8) + (k0 >> 5) + kt_l))*64 + lane)*8)
          = *(const uint4*)tmp;
    }
    return;
  }

  // scalars
  const int blk = u - 1120;
  const int b = blk*4 + (t >> 6), l = t & 63;
  const float4 xv = *(const float4*)(x + b*UDIM + l*4);
  float s0 = xv.x*xv.x + xv.y*xv.y + xv.z*xv.z + xv.w*xv.w;
  const float4 pv = *(const float4*)(prev + b*UDIM + l*4);
  float s1 = pv.x*pv.x + pv.y*pv.y + pv.z*pv.z + pv.w*pv.w;
  float s2 = 0.f;
#pragma unroll
  for (int e = 0; e < 4; ++e)
    s2 += S[(size_t)b*MATN + (size_t)(l*4 + e)*257];
  for (int off = 32; off; off >>= 1) {
    s0 += __shfl_down(s0, off);
    s1 += __shfl_down(s1, off);
    s2 += __shfl_down(s2, off);
  }
  if (l == 0) {
    atomicAdd(&scal[b], s0);
    atomicAdd(&scal[64 + b], s1);
    atomicAdd(&scal[128 + b], s2);
  }
}

// ---------------------------------------------------------------------------
// gates_zr (verified round 5/7/8): z, r, gz, gr, gin + gg atomics.  grid (4,2).
// ---------------------------------------------------------------------------
__global__ __launch_bounds__(256) void gates_zr(
    const float* __restrict__ x, const float* __restrict__ prev,
    const __bf16* __restrict__ Fu_z, const __bf16* __restrict__ Fw_z,
    const __bf16* __restrict__ Fu_r, const __bf16* __restrict__ Fw_r,
    float* __restrict__ zb, float* __restrict__ rb,
    float* __restrict__ gzb, float* __restrict__ grb,
    float* __restrict__ gin, float* __restrict__ scal)
{
  const int jt = blockIdx.x;
  const int gate = blockIdx.y;
  const __bf16* FU = gate ? Fu_r : Fu_z;
  const __bf16* FW = gate ? Fw_r : Fw_z;
  const int t = threadIdx.x, w = t >> 6, l = t & 63, r = l & 15, q = l >> 4;
  const int mrow = w*16 + r;

  f32x4 acc[4] = {};
#pragma unroll
  for (int ks = 0; ks < 16; ++ks) {
    const int k0 = ks*32;
    const float* asrc; const __bf16* B; int kk;
    if (k0 < 256) { asrc = x    + (size_t)mrow*UDIM + k0         + q*8; B = FU; kk = k0; }
    else          { asrc = prev + (size_t)mrow*UDIM + (k0 - 256) + q*8; B = FW; kk = k0 - 256; }
    const bf16x8 af = cvt8(asrc);
#pragma unroll
    for (int ni = 0; ni < 4; ++ni) {
      const bf16x8 bv = frag_load(B, jt*4 + ni, kk >> 5, l);
      acc[ni] = __builtin_amdgcn_mfma_f32_16x16x32_bf16(af, bv, acc[ni], 0, 0, 0);
    }
  }

  if (gate == 0) {
#pragma unroll
    for (int ni = 0; ni < 4; ++ni) {
      const int n = jt*64 + ni*16 + r;
#pragma unroll
      for (int v = 0; v < 4; ++v) {
        const int m = w*16 + q*4 + v;
        const float zv = sigmoidf_(acc[ni][v]);
        zb[m*UDIM + n]  = zv;
        gzb[m*UDIM + n] = zv * (1.f - zv);
      }
    }
  } else {
    float ggp[4] = {0.f, 0.f, 0.f, 0.f};
#pragma unroll
    for (int ni = 0; ni < 4; ++ni) {
      const int n = jt*64 + ni*16 + r;
#pragma unroll
      for (int v = 0; v < 4; ++v) {
        const int m = w*16 + q*4 + v;
        const float rv = sigmoidf_(acc[ni][v]);
        const float pv = prev[m*UDIM + n];
        const float g2 = pv * rv;
        rb[m*UDIM + n]  = rv;
        grb[m*UDIM + n] = rv * (1.f - rv);
        gin[m*UDIM + n] = g2;
        ggp[v] += g2 * g2;
      }
    }
#pragma unroll
    for (int s = 1; s < 16; s <<= 1)
#pragma unroll
      for (int v = 0; v < 4; ++v) ggp[v] += __shfl_xor(ggp[v], s);
    if (r == 0)
#pragma unroll
      for (int v = 0; v < 4; ++v)
        atomicAdd(&scal[192 + w*16 + q*4 + v], ggp[v]);
  }
}

// ---------------------------------------------------------------------------
// quad_zr (+ gates_h riding as blocks 1024..1027):
//   bid < 1024: one 16-row strip of one batch, both gates:
//     left  T_g = Wt_g[strip] @ S_b (Sf fragment-direct) -> LDS;
//     right Q_g = T_g @ W_g + epilogue (Sc coalesced bf16 reads):
//       z -> Szb (C-linear), r -> G (fragment-direct) + trG atomics.
//   bid >= 1024: gates_h (h, gh, mu_out), jt = bid-1024.
// ---------------------------------------------------------------------------
__global__ __launch_bounds__(256, 4) void quad_zr(
    const __bf16* __restrict__ Sf, const __bf16* __restrict__ Sc,
    const float* __restrict__ x, const float* __restrict__ gin,
    const float* __restrict__ prev, const float* __restrict__ rb,
    const float* __restrict__ zb,
    const float* __restrict__ gzb, const float* __restrict__ grb,
    const float* __restrict__ wz_s, const float* __restrict__ uz_s,
    const float* __restrict__ wr_s, const float* __restrict__ ur_s,
    const __bf16* __restrict__ Fw_z, const __bf16* __restrict__ Fw_r,
    const __bf16* __restrict__ Fu_h, const __bf16* __restrict__ Fw_h,
    float* __restrict__ scal, __bf16* __restrict__ Szb, __bf16* __restrict__ G,
    float* __restrict__ hb, float* __restrict__ ghb, float* __restrict__ mu_out)
{
  __shared__ __align__(16) __bf16 Tz[16*PITCH];
  __shared__ __align__(16) __bf16 Tr[16*PITCH];
  const int bid = blockIdx.x;
  const int t = threadIdx.x, w = t >> 6, l = t & 63, r = l & 15, q = l >> 4;

  if (bid >= 1024) {
    // ---- gates_h ----
    const int jt = bid - 1024;
    const int mrow = w*16 + r;
    f32x4 acc[4] = {};
#pragma unroll
    for (int ks = 0; ks < 16; ++ks) {
      const int k0 = ks*32;
      const float* asrc; const __bf16* B; int kk;
      if (k0 < 256) { asrc = x   + (size_t)mrow*UDIM + k0         + q*8; B = Fu_h; kk = k0; }
      else          { asrc = gin + (size_t)mrow*UDIM + (k0 - 256) + q*8; B = Fw_h; kk = k0 - 256; }
      const bf16x8 af = cvt8(asrc);
#pragma unroll
      for (int ni = 0; ni < 4; ++ni) {
        const bf16x8 bv = frag_load(B, jt*4 + ni, kk >> 5, l);
        acc[ni] = __builtin_amdgcn_mfma_f32_16x16x32_bf16(af, bv, acc[ni], 0, 0, 0);
      }
    }
#pragma unroll
    for (int ni = 0; ni < 4; ++ni) {
      const int n = jt*64 + ni*16 + r;
#pragma unroll
      for (int v = 0; v < 4; ++v) {
        const int m = w*16 + q*4 + v;
        const float hv = tanhf(acc[ni][v]);
        const float zv = zb[m*UDIM + n];
        hb[m*UDIM + n]  = hv;
        ghb[m*UDIM + n] = 1.f - hv*hv;
        mu_out[m*UDIM + n] = zv * prev[m*UDIM + n] + (1.f - zv) * hv;
      }
    }
    return;
  }

  const int s = bid >> 6, b = bid & 63;
  const size_t sb = (size_t)b * MATN;
  const __bf16* Sfb = Sf + sb;

  // ---- left GEMM ----
  f32x4 az[4] = {}, ar[4] = {};
#pragma unroll
  for (int kt = 0; kt < 8; ++kt) {
    const bf16x8 afz = frag_load(Fw_z, s, kt, l);
    const bf16x8 afr = frag_load(Fw_r, s, kt, l);
#pragma unroll
    for (int ct = 0; ct < 4; ++ct) {
      const bf16x8 bv = frag_load(Sfb, w*4 + ct, kt, l);
      az[ct] = __builtin_amdgcn_mfma_f32_16x16x32_bf16(afz, bv, az[ct], 0, 0, 0);
      ar[ct] = __builtin_amdgcn_mfma_f32_16x16x32_bf16(afr, bv, ar[ct], 0, 0, 0);
    }
  }
#pragma unroll
  for (int ct = 0; ct < 4; ++ct)
#pragma unroll
    for (int v = 0; v < 4; ++v) {
      const int row = q*4 + v, col = w*64 + ct*16 + r;
      Tz[row*PITCH + col] = (__bf16)az[ct][v];
      Tr[row*PITCH + col] = (__bf16)ar[ct][v];
    }
  __syncthreads();

  // ---- right GEMM ----
  f32x4 qz[4] = {}, qr[4] = {};
#pragma unroll
  for (int kt = 0; kt < 8; ++kt) {
    const bf16x8 atz = *(const bf16x8*)&Tz[r*PITCH + kt*32 + q*8];
    const bf16x8 atr = *(const bf16x8*)&Tr[r*PITCH + kt*32 + q*8];
#pragma unroll
    for (int ct = 0; ct < 4; ++ct) {
      const bf16x8 bz = frag_load(Fw_z, w*4 + ct, kt, l);
      const bf16x8 br = frag_load(Fw_r, w*4 + ct, kt, l);
      qz[ct] = __builtin_amdgcn_mfma_f32_16x16x32_bf16(atz, bz, qz[ct], 0, 0, 0);
      qr[ct] = __builtin_amdgcn_mfma_f32_16x16x32_bf16(atr, br, qr[ct], 0, 0, 0);
    }
  }

  const float xx = scal[b];
  const float dscal = scal[64 + b] + scal[128 + b];   // pp + trS
  const int ib = s*16 + q*4;

  // Sc strip values (coalesced 32B/thread)
  const __bf16* scp = Sc + ((size_t)(b*16 + s)*256 + t)*16;
  __align__(16) __bf16 sc16[16];
  *(uint4*)&sc16[0] = *(const uint4*)scp;
  *(uint4*)&sc16[8] = *(const uint4*)(scp + 8);

  // ---- z epilogue -> Szb ----
  {
    const f32x4 g4 = *(const f32x4*)(gzb + b*UDIM + ib);
    __align__(16) __bf16 o16[16];
#pragma unroll
    for (int ct = 0; ct < 4; ++ct) {
      const int j = (w*4 + ct)*16 + r;
      const float gj = gzb[b*UDIM + j];
#pragma unroll
      for (int v = 0; v < 4; ++v) {
        const int i = ib + v;
        float qv = qz[ct][v];
        if (i == j) qv += dscal*softplusf(wz_s[i]) + xx*softplusf(uz_s[i]);
        o16[ct*4 + v] = (__bf16)(qv * g4[v] * gj);
      }
    }
    __bf16* dst = Szb + ((size_t)(b*16 + s)*256 + t)*16;
    *(uint4*)dst       = *(const uint4*)&o16[0];
    *(uint4*)(dst + 8) = *(const uint4*)&o16[8];
  }

  // ---- r epilogue -> sigma_g + trG ----
  float gvals[16];
  float trg = 0.f;
  {
    const f32x4 g4 = *(const f32x4*)(grb + b*UDIM + ib);
    const f32x4 p4 = *(const f32x4*)(prev + b*UDIM + ib);
    const f32x4 r4 = *(const f32x4*)(rb + b*UDIM + ib);
#pragma unroll
    for (int ct = 0; ct < 4; ++ct) {
      const int j = (w*4 + ct)*16 + r;
      const float gj = grb[b*UDIM + j];
      const float pj = prev[b*UDIM + j];
      const float rj = rb[b*UDIM + j];
#pragma unroll
      for (int v = 0; v < 4; ++v) {
        const int i = ib + v;
        float qv = qr[ct][v];
        if (i == j) qv += dscal*softplusf(wr_s[i]) + xx*softplusf(ur_s[i]);
        const float Sg = qv * g4[v] * gj;
        const float sv = (float)sc16[ct*4 + v];
        const float go = Sg*(sv + p4[v]*pj) + r4[v]*rj*sv;
        gvals[ct*4 + v] = go;
        if (i == j) trg += go;
      }
    }
  }
  if (trg != 0.f) atomicAdd(&scal[256 + b], trg);

  // ---- bounce sigma_g strip -> fragment-direct G (reuse Tz) ----
  __syncthreads();
#pragma unroll
  for (int ct = 0; ct < 4; ++ct)
#pragma unroll
    for (int v = 0; v < 4; ++v)
      Tz[(q*4 + v)*PITCH + w*64 + ct*16 + r] = (__bf16)gvals[ct*4 + v];
  __syncthreads();
#pragma unroll
  for (int ee = 0; ee < 2; ++ee) {
    const int e = t + ee*256;
    const int kt = e >> 6, le = e & 63;
    const uint4 vv = *(const uint4*)&Tz[(le & 15)*PITCH + kt*32 + (le >> 4)*8];
    *(uint4*)(G + sb + (((size_t)(s*8 + kt))*64 + le)*8) = vv;
  }
}

// ---------------------------------------------------------------------------
// quad_h: one 16-row strip of one batch.
//   left  T_h = Wt_h[strip] @ G_b ; right Q_h = T_h @ W_h + final epilogue
//   (Sc + Szb coalesced bf16 reads) -> out_sig fp32.
// ---------------------------------------------------------------------------
__global__ __launch_bounds__(256, 4) void quad_h(
    const __bf16* __restrict__ Sc, const __bf16* __restrict__ Szb,
    const float* __restrict__ prev, const float* __restrict__ zb,
    const float* __restrict__ hb, const float* __restrict__ ghb,
    const float* __restrict__ wh_s, const float* __restrict__ uh_s,
    const __bf16* __restrict__ Fw_h, const __bf16* __restrict__ G,
    const float* __restrict__ scal, float* __restrict__ out_sig)
{
  const int bid = blockIdx.x;
  const int s = bid >> 6, b = bid & 63;
  const size_t sb = (size_t)b * MATN;
  const int t = threadIdx.x, w = t >> 6, l = t & 63, r = l & 15, q = l >> 4;
  const __bf16* Gb = G + sb;

  __shared__ __align__(16) __bf16 Th[16*PITCH];

  f32x4 ah[4] = {};
#pragma unroll
  for (int kt = 0; kt < 8; ++kt) {
    const bf16x8 af = frag_load(Fw_h, s, kt, l);
#pragma unroll
    for (int ct = 0; ct < 4; ++ct) {
      const bf16x8 bv = frag_load(Gb, w*4 + ct, kt, l);
      ah[ct] = __builtin_amdgcn_mfma_f32_16x16x32_bf16(af, bv, ah[ct], 0, 0, 0);
    }
  }
#pragma unroll
  for (int ct = 0; ct < 4; ++ct)
#pragma unroll
    for (int v = 0; v < 4; ++v)
      Th[(q*4 + v)*PITCH + w*64 + ct*16 + r] = (__bf16)ah[ct][v];
  __syncthreads();

  f32x4 qh[4] = {};
#pragma unroll
  for (int kt = 0; kt < 8; ++kt) {
    const bf16x8 at = *(const bf16x8*)&Th[r*PITCH + kt*32 + q*8];
#pragma unroll
    for (int ct = 0; ct < 4; ++ct) {
      const bf16x8 bv = frag_load(Fw_h, w*4 + ct, kt, l);
      qh[ct] = __builtin_amdgcn_mfma_f32_16x16x32_bf16(at, bv, qh[ct], 0, 0, 0);
    }
  }

  const float xx = scal[b];
  const float dscal = scal[192 + b] + scal[256 + b];  // gg + trG
  const int ib = s*16 + q*4;

  const __bf16* szp = Szb + ((size_t)(b*16 + s)*256 + t)*16;
  __align__(16) __bf16 sz16[16];
  *(uint4*)&sz16[0] = *(const uint4*)szp;
  *(uint4*)&sz16[8] = *(const uint4*)(szp + 8);

  const __bf16* scp = Sc + ((size_t)(b*16 + s)*256 + t)*16;
  __align__(16) __bf16 sc16[16];
  *(uint4*)&sc16[0] = *(const uint4*)scp;
  *(uint4*)&sc16[8] = *(const uint4*)(scp + 8);

  const f32x4 g4 = *(const f32x4*)(ghb + b*UDIM + ib);
  const f32x4 p4 = *(const f32x4*)(prev + b*UDIM + ib);
  const f32x4 z4 = *(const f32x4*)(zb + b*UDIM + ib);
  const f32x4 h4 = *(const f32x4*)(hb + b*UDIM + ib);

#pragma unroll
  for (int ct = 0; ct < 4; ++ct) {
    const int j = (w*4 + ct)*16 + r;
    const float gj = ghb[b*UDIM + j];
    const float pj = prev[b*UDIM + j];
    const float zj = zb[b*UDIM + j];
    const float hj = hb[b*UDIM + j];
#pragma unroll
    for (int v = 0; v < 4; ++v) {
      const int i = ib + v;
      float qv = qh[ct][v];
      if (i == j) qv += dscal*softplusf(wh_s[i]) + xx*softplusf(uh_s[i]);
      const float Sg = qv * g4[v] * gj;
      const float sv = (float)sc16[ct*4 + v];
      const float sz = (float)sz16[ct*4 + v];
      float val = sv*(sz + z4[v]*zj)
                + sz*(p4[v] - h4[v])*(pj - hj)
                + Sg*(sz + (1.f - z4[v])*(1.f - zj));
      if (!isfinite(val)) val = 0.f;
      if (i == j) val = fabsf(val);
      out_sig[sb + (size_t)i*UDIM + j] = val;
    }
  }
}

// ---------------------------------------------------------------------------
extern "C" void kernel_launch(void* const* d_in, const int* in_sizes, int n_in,
                              void* d_out, int out_size, void* d_ws, size_t ws_size,
                              hipStream_t stream) {
  const float* x    = (const float*)d_in[0];
  const float* prev = (const float*)d_in[1];
  const float* S    = (const float*)d_in[2];
  const float* Uz   = (const float*)d_in[3];
  const float* uz_s = (const float*)d_in[4];
  const float* Wz   = (const float*)d_in[5];
  const float* wz_s = (const float*)d_in[6];
  const float* Ur   = (const float*)d_in[7];
  const float* ur_s = (const float*)d_in[8];
  const float* Wr   = (const float*)d_in[9];
  const float* wr_s = (const float*)d_in[10];
  const float* Uh   = (const float*)d_in[11];
  const float* uh_s = (const float*)d_in[12];
  const float* Wh   = (const float*)d_in[13];
  const float* wh_s = (const float*)d_in[14];

  float* out_mu  = (float*)d_out;
  float* out_sig = out_mu + BATCH*UDIM;

  float* ws   = (float*)d_ws;
  float* zb   = ws;
  float* rb   = zb  + BATCH*UDIM;
  float* gzb  = rb  + BATCH*UDIM;
  float* grb  = gzb + BATCH*UDIM;
  float* gin  = grb + BATCH*UDIM;
  float* hb   = gin + BATCH*UDIM;
  float* ghb  = hb  + BATCH*UDIM;
  float* scal = ghb + BATCH*UDIM;            // 512 floats
  __bf16* bws  = (__bf16*)(scal + 512);
  __bf16* Fu_z = bws;
  __bf16* Fw_z = Fu_z + MATN;
  __bf16* Fu_r = Fw_z + MATN;
  __bf16* Fw_r = Fu_r + MATN;
  __bf16* Fu_h = Fw_r + MATN;
  __bf16* Fw_h = Fu_h + MATN;
  const size_t BIG = (size_t)BATCH * MATN;
  __bf16* Szb = Fw_h + MATN;                 // [B,16,256,16] bf16 C-linear
  __bf16* G   = Szb + BIG;                   // [B,U,U] bf16 fragment-direct
  __bf16* Sf  = G + BIG;                     // [B,U,U] bf16 fragment-direct
  __bf16* Sc  = Sf + BIG;                    // [B,U,U] bf16 C-linear

  hipMemsetAsync(scal, 0, 512*sizeof(float), stream);

  prepk<<<dim3(1136), 256, 0, stream>>>(S, x, prev, Uz, Wz, Ur, Wr, Uh, Wh,
      Fu_z, Fw_z, Fu_r, Fw_r, Fu_h, Fw_h, Sf, Sc, scal);
  gates_zr<<<dim3(4,2), 256, 0, stream>>>(x, prev, Fu_z, Fw_z, Fu_r, Fw_r,
      zb, rb, gzb, grb, gin, scal);
  quad_zr<<<dim3(1028), 256, 0, stream>>>(Sf, Sc, x, gin, prev, rb, zb,
      gzb, grb, wz_s, uz_s, wr_s, ur_s, Fw_z, Fw_r, Fu_h, Fw_h,
      scal, Szb, G, hb, ghb, out_mu);
  quad_h<<<dim3(1024), 256, 0, stream>>>(Sc, Szb, prev, zb, hb, ghb,
      wh_s, uh_s, Fw_h, G, scal, out_sig);
}

// Round 10
// 171.199 us; speedup vs baseline: 1.1559x; 1.1559x over previous
//
#include <hip/hip_runtime.h>
#include <math.h>

#define UDIM 256
#define BATCH 64
#define MATN 65536   // 256*256
#define PITCH 280    // LDS row pitch (bf16): 560B = 16B-aligned

typedef __bf16 bf16x8 __attribute__((ext_vector_type(8)));
typedef float  f32x4  __attribute__((ext_vector_type(4)));

__device__ __forceinline__ float softplusf(float x) { return log1pf(expf(x)); }
__device__ __forceinline__ float sigmoidf_(float x) { return 1.f/(1.f+expf(-x)); }

// Fragment-direct layout (verified rounds 4-9): chunk(rt,kt) = rows rt*16..+15
// x k kt*32..+31; lane = (row&15) | ((k>>3)&3)<<4; 8 contiguous bf16 per lane.
__device__ __forceinline__ bf16x8 frag_load(const __bf16* base, int rt, int kt, int lane) {
  return *(const bf16x8*)(base + (((size_t)(rt*8 + kt))*64 + lane)*8);
}

__device__ __forceinline__ bf16x8 cvt8(const float* p) {
  const float4 f0 = *(const float4*)p;
  const float4 f1 = *(const float4*)(p + 4);
  bf16x8 v;
  v[0]=(__bf16)f0.x; v[1]=(__bf16)f0.y; v[2]=(__bf16)f0.z; v[3]=(__bf16)f0.w;
  v[4]=(__bf16)f1.x; v[5]=(__bf16)f1.y; v[6]=(__bf16)f1.z; v[7]=(__bf16)f1.w;
  return v;
}

// ---------------------------------------------------------------------------
// prep_w: grid 112.  u<96: fragment-direct bf16 weight transposes;
// u>=96: scalar reductions xx, pp, trS.
// scal: xx[0..63], pp[64..127], trS[128..191], gg[192..255], trG[256..319]
// ---------------------------------------------------------------------------
__global__ __launch_bounds__(256) void prep_w(
    const float* __restrict__ Uz, const float* __restrict__ Wz,
    const float* __restrict__ Ur, const float* __restrict__ Wr,
    const float* __restrict__ Uh, const float* __restrict__ Wh,
    __bf16* __restrict__ Fu_z, __bf16* __restrict__ Fw_z,
    __bf16* __restrict__ Fu_r, __bf16* __restrict__ Fw_r,
    __bf16* __restrict__ Fu_h, __bf16* __restrict__ Fw_h,
    const float* __restrict__ S, const float* __restrict__ x,
    const float* __restrict__ prev, float* __restrict__ scal)
{
  const int u = blockIdx.x;
  const int t = threadIdx.x;
  if (u >= 96) {
    const int blk = u - 96;
    const int b = blk*4 + (t >> 6), l = t & 63;
    const float4 xv = *(const float4*)(x + b*UDIM + l*4);
    float s0 = xv.x*xv.x + xv.y*xv.y + xv.z*xv.z + xv.w*xv.w;
    const float4 pv = *(const float4*)(prev + b*UDIM + l*4);
    float s1 = pv.x*pv.x + pv.y*pv.y + pv.z*pv.z + pv.w*pv.w;
    float s2 = 0.f;
#pragma unroll
    for (int e = 0; e < 4; ++e)
      s2 += S[(size_t)b*MATN + (size_t)(l*4 + e)*257];
    for (int off = 32; off; off >>= 1) {
      s0 += __shfl_down(s0, off);
      s1 += __shfl_down(s1, off);
      s2 += __shfl_down(s2, off);
    }
    if (l == 0) {
      atomicAdd(&scal[b], s0);
      atomicAdd(&scal[64 + b], s1);
      atomicAdd(&scal[128 + b], s2);
    }
    return;
  }
  const int mat = u >> 4, tl = u & 15;
  const int n0 = (tl & 3)*64, k0 = (tl >> 2)*64;
  const float* W; __bf16* F;
  switch (mat) {
    case 0: W = Uz; F = Fu_z; break;  case 1: W = Wz; F = Fw_z; break;
    case 2: W = Ur; F = Fu_r; break;  case 3: W = Wr; F = Fw_r; break;
    case 4: W = Uh; F = Fu_h; break;  default: W = Wh; F = Fw_h; break;
  }
  __shared__ float tile[64][65];
  const int tx = t & 15, ty = t >> 4;
#pragma unroll
  for (int rr = 0; rr < 4; ++rr) {
    const int row = ty*4 + rr;
    const float4 f = *(const float4*)(W + (size_t)(k0 + row)*UDIM + n0 + tx*4);
    tile[row][tx*4+0] = f.x; tile[row][tx*4+1] = f.y;
    tile[row][tx*4+2] = f.z; tile[row][tx*4+3] = f.w;
  }
  __syncthreads();
#pragma unroll
  for (int ss = 0; ss < 2; ++ss) {
    const int s = t + ss*256;
    const int rt_l = s >> 7, kt_l = (s >> 6) & 1, lane = s & 63;
    const int nl = rt_l*16 + (lane & 15), kb = kt_l*32 + (lane >> 4)*8;
    __align__(16) __bf16 tmp[8];
#pragma unroll
    for (int e = 0; e < 8; ++e) tmp[e] = (__bf16)tile[kb + e][nl];
    *(uint4*)(F + (((size_t)((((n0 >> 4) + rt_l)*8) + (k0 >> 5) + kt_l))*64 + lane)*8)
        = *(const uint4*)tmp;
  }
}

// ---------------------------------------------------------------------------
// sconv_gates: grid 1032.  bid<8: gates_zr (latency-long, dispatched FIRST,
// hidden under the streaming blocks); bid>=8: S -> Sf fragment-direct bf16.
// ---------------------------------------------------------------------------
__global__ __launch_bounds__(256) void sconv_gates(
    const float* __restrict__ S, __bf16* __restrict__ Sf,
    const float* __restrict__ x, const float* __restrict__ prev,
    const __bf16* __restrict__ Fu_z, const __bf16* __restrict__ Fw_z,
    const __bf16* __restrict__ Fu_r, const __bf16* __restrict__ Fw_r,
    float* __restrict__ zb, float* __restrict__ rb,
    float* __restrict__ gzb, float* __restrict__ grb,
    float* __restrict__ gin, float* __restrict__ scal)
{
  const int bid = blockIdx.x;
  const int t = threadIdx.x, w = t >> 6, l = t & 63, r = l & 15, q = l >> 4;

  if (bid < 8) {
    // ---- gates_zr (verified rounds 5-9) ----
    const int jt = bid & 3, gate = bid >> 2;
    const __bf16* FU = gate ? Fu_r : Fu_z;
    const __bf16* FW = gate ? Fw_r : Fw_z;
    const int mrow = w*16 + r;
    f32x4 acc[4] = {};
#pragma unroll
    for (int ks = 0; ks < 16; ++ks) {
      const int k0 = ks*32;
      const float* asrc; const __bf16* B; int kk;
      if (k0 < 256) { asrc = x    + (size_t)mrow*UDIM + k0         + q*8; B = FU; kk = k0; }
      else          { asrc = prev + (size_t)mrow*UDIM + (k0 - 256) + q*8; B = FW; kk = k0 - 256; }
      const bf16x8 af = cvt8(asrc);
#pragma unroll
      for (int ni = 0; ni < 4; ++ni) {
        const bf16x8 bv = frag_load(B, jt*4 + ni, kk >> 5, l);
        acc[ni] = __builtin_amdgcn_mfma_f32_16x16x32_bf16(af, bv, acc[ni], 0, 0, 0);
      }
    }
    if (gate == 0) {
#pragma unroll
      for (int ni = 0; ni < 4; ++ni) {
        const int n = jt*64 + ni*16 + r;
#pragma unroll
        for (int v = 0; v < 4; ++v) {
          const int m = w*16 + q*4 + v;
          const float zv = sigmoidf_(acc[ni][v]);
          zb[m*UDIM + n]  = zv;
          gzb[m*UDIM + n] = zv * (1.f - zv);
        }
      }
    } else {
      float ggp[4] = {0.f, 0.f, 0.f, 0.f};
#pragma unroll
      for (int ni = 0; ni < 4; ++ni) {
        const int n = jt*64 + ni*16 + r;
#pragma unroll
        for (int v = 0; v < 4; ++v) {
          const int m = w*16 + q*4 + v;
          const float rv = sigmoidf_(acc[ni][v]);
          const float pv = prev[m*UDIM + n];
          const float g2 = pv * rv;
          rb[m*UDIM + n]  = rv;
          grb[m*UDIM + n] = rv * (1.f - rv);
          gin[m*UDIM + n] = g2;
          ggp[v] += g2 * g2;
        }
      }
#pragma unroll
      for (int s = 1; s < 16; s <<= 1)
#pragma unroll
        for (int v = 0; v < 4; ++v) ggp[v] += __shfl_xor(ggp[v], s);
      if (r == 0)
#pragma unroll
        for (int v = 0; v < 4; ++v)
          atomicAdd(&scal[192 + w*16 + q*4 + v], ggp[v]);
    }
    return;
  }

  // ---- sconvf (verified round 8) ----
  const int u = bid - 8;
  const int bx = u & 3, by = (u >> 2) & 3, b = u >> 4;
  const size_t sb = (size_t)b * MATN;
#pragma unroll
  for (int ss = 0; ss < 2; ++ss) {
    const int s = t + ss*256;
    const int chunk = s >> 6, lane = s & 63;
    const int rt_l = chunk >> 1, kt_l = chunk & 1;
    const int row = by*64 + rt_l*16 + (lane & 15);
    const int col = bx*64 + kt_l*32 + (lane >> 4)*8;
    const bf16x8 v = cvt8(S + sb + (size_t)row*UDIM + col);
    *(bf16x8*)(Sf + sb + (((size_t)((by*4 + rt_l)*8 + bx*2 + kt_l))*64 + lane)*8) = v;
  }
}

// ---------------------------------------------------------------------------
// quad_zr_gh: grid 1028.  bid<4: gates_h (dispatched first);
// bid>=4: EXACT round-8-bench quad_zr body (16-row strip, both gates,
// fp32-S scattered epilogue).
// ---------------------------------------------------------------------------
__global__ __launch_bounds__(256, 4) void quad_zr_gh(
    const float* __restrict__ S, const __bf16* __restrict__ Sf,
    const float* __restrict__ prev,
    const float* __restrict__ rb, const float* __restrict__ gzb,
    const float* __restrict__ grb,
    const float* __restrict__ wz_s, const float* __restrict__ uz_s,
    const float* __restrict__ wr_s, const float* __restrict__ ur_s,
    const __bf16* __restrict__ Fw_z, const __bf16* __restrict__ Fw_r,
    float* __restrict__ scal, __bf16* __restrict__ Szb, __bf16* __restrict__ G,
    const float* __restrict__ x, const float* __restrict__ gin,
    const float* __restrict__ zb,
    const __bf16* __restrict__ Fu_h, const __bf16* __restrict__ Fw_h,
    float* __restrict__ hb, float* __restrict__ ghb, float* __restrict__ mu_out)
{
  const int bid = blockIdx.x;
  const int t = threadIdx.x, w = t >> 6, l = t & 63, r = l & 15, q = l >> 4;

  if (bid < 4) {
    // ---- gates_h (verified rounds 5-9) ----
    const int jt = bid;
    const int mrow = w*16 + r;
    f32x4 acc[4] = {};
#pragma unroll
    for (int ks = 0; ks < 16; ++ks) {
      const int k0 = ks*32;
      const float* asrc; const __bf16* B; int kk;
      if (k0 < 256) { asrc = x   + (size_t)mrow*UDIM + k0         + q*8; B = Fu_h; kk = k0; }
      else          { asrc = gin + (size_t)mrow*UDIM + (k0 - 256) + q*8; B = Fw_h; kk = k0 - 256; }
      const bf16x8 af = cvt8(asrc);
#pragma unroll
      for (int ni = 0; ni < 4; ++ni) {
        const bf16x8 bv = frag_load(B, jt*4 + ni, kk >> 5, l);
        acc[ni] = __builtin_amdgcn_mfma_f32_16x16x32_bf16(af, bv, acc[ni], 0, 0, 0);
      }
    }
#pragma unroll
    for (int ni = 0; ni < 4; ++ni) {
      const int n = jt*64 + ni*16 + r;
#pragma unroll
      for (int v = 0; v < 4; ++v) {
        const int m = w*16 + q*4 + v;
        const float hv = tanhf(acc[ni][v]);
        const float zv = zb[m*UDIM + n];
        hb[m*UDIM + n]  = hv;
        ghb[m*UDIM + n] = 1.f - hv*hv;
        mu_out[m*UDIM + n] = zv * prev[m*UDIM + n] + (1.f - zv) * hv;
      }
    }
    return;
  }

  const int id = bid - 4;
  const int s = id >> 6, b = id & 63;   // strip 0..15, batch 0..63
  const size_t sb = (size_t)b * MATN;
  const __bf16* Sfb = Sf + sb;

  __shared__ __align__(16) __bf16 Tz[16*PITCH];
  __shared__ __align__(16) __bf16 Tr[16*PITCH];

  // ---- left GEMM: T strips ----
  f32x4 az[4] = {}, ar[4] = {};
#pragma unroll
  for (int kt = 0; kt < 8; ++kt) {
    const bf16x8 afz = frag_load(Fw_z, s, kt, l);
    const bf16x8 afr = frag_load(Fw_r, s, kt, l);
#pragma unroll
    for (int ct = 0; ct < 4; ++ct) {
      const bf16x8 bv = frag_load(Sfb, w*4 + ct, kt, l);
      az[ct] = __builtin_amdgcn_mfma_f32_16x16x32_bf16(afz, bv, az[ct], 0, 0, 0);
      ar[ct] = __builtin_amdgcn_mfma_f32_16x16x32_bf16(afr, bv, ar[ct], 0, 0, 0);
    }
  }
#pragma unroll
  for (int ct = 0; ct < 4; ++ct)
#pragma unroll
    for (int v = 0; v < 4; ++v) {
      const int row = q*4 + v, col = w*64 + ct*16 + r;
      Tz[row*PITCH + col] = (__bf16)az[ct][v];
      Tr[row*PITCH + col] = (__bf16)ar[ct][v];
    }
  __syncthreads();

  // ---- right GEMM from LDS ----
  f32x4 qz[4] = {}, qr[4] = {};
#pragma unroll
  for (int kt = 0; kt < 8; ++kt) {
    const bf16x8 atz = *(const bf16x8*)&Tz[r*PITCH + kt*32 + q*8];
    const bf16x8 atr = *(const bf16x8*)&Tr[r*PITCH + kt*32 + q*8];
#pragma unroll
    for (int ct = 0; ct < 4; ++ct) {
      const bf16x8 bz = frag_load(Fw_z, w*4 + ct, kt, l);
      const bf16x8 br = frag_load(Fw_r, w*4 + ct, kt, l);
      qz[ct] = __builtin_amdgcn_mfma_f32_16x16x32_bf16(atz, bz, qz[ct], 0, 0, 0);
      qr[ct] = __builtin_amdgcn_mfma_f32_16x16x32_bf16(atr, br, qr[ct], 0, 0, 0);
    }
  }

  const float xx = scal[b];
  const float dscal = scal[64 + b] + scal[128 + b];   // pp + trS
  const int ib = s*16 + q*4;

  // ---- z epilogue -> Szb (C-linear bf16) ----
  {
    const f32x4 g4 = *(const f32x4*)(gzb + b*UDIM + ib);
    __align__(16) __bf16 o16[16];
#pragma unroll
    for (int ct = 0; ct < 4; ++ct) {
      const int j = (w*4 + ct)*16 + r;
      const float gj = gzb[b*UDIM + j];
#pragma unroll
      for (int v = 0; v < 4; ++v) {
        const int i = ib + v;
        float qv = qz[ct][v];
        if (i == j) qv += dscal*softplusf(wz_s[i]) + xx*softplusf(uz_s[i]);
        o16[ct*4 + v] = (__bf16)(qv * g4[v] * gj);
      }
    }
    __bf16* dst = Szb + ((size_t)(b*16 + s)*256 + t)*16;
    *(uint4*)dst       = *(const uint4*)&o16[0];
    *(uint4*)(dst + 8) = *(const uint4*)&o16[8];
  }

  // ---- r epilogue -> sigma_g + trG ----
  float gvals[16];
  float trg = 0.f;
  {
    const f32x4 g4 = *(const f32x4*)(grb + b*UDIM + ib);
    const f32x4 p4 = *(const f32x4*)(prev + b*UDIM + ib);
    const f32x4 r4 = *(const f32x4*)(rb + b*UDIM + ib);
#pragma unroll
    for (int ct = 0; ct < 4; ++ct) {
      const int j = (w*4 + ct)*16 + r;
      const float gj = grb[b*UDIM + j];
      const float pj = prev[b*UDIM + j];
      const float rj = rb[b*UDIM + j];
#pragma unroll
      for (int v = 0; v < 4; ++v) {
        const int i = ib + v;
        float qv = qr[ct][v];
        if (i == j) qv += dscal*softplusf(wr_s[i]) + xx*softplusf(ur_s[i]);
        const float Sg = qv * g4[v] * gj;
        const float sv = S[sb + (size_t)i*UDIM + j];
        const float go = Sg*(sv + p4[v]*pj) + r4[v]*rj*sv;
        gvals[ct*4 + v] = go;
        if (i == j) trg += go;
      }
    }
  }
  if (trg != 0.f) atomicAdd(&scal[256 + b], trg);

  // ---- bounce sigma_g strip -> fragment-direct G (reuse Tz) ----
  __syncthreads();
#pragma unroll
  for (int ct = 0; ct < 4; ++ct)
#pragma unroll
    for (int v = 0; v < 4; ++v)
      Tz[(q*4 + v)*PITCH + w*64 + ct*16 + r] = (__bf16)gvals[ct*4 + v];
  __syncthreads();
#pragma unroll
  for (int ee = 0; ee < 2; ++ee) {
    const int e = t + ee*256;
    const int kt = e >> 6, le = e & 63;
    const uint4 vv = *(const uint4*)&Tz[(le & 15)*PITCH + kt*32 + (le >> 4)*8];
    *(uint4*)(G + sb + (((size_t)(s*8 + kt))*64 + le)*8) = vv;
  }
}

// ---------------------------------------------------------------------------
// quad_h (EXACT round-8-bench version): one 16-row strip of one batch.
// ---------------------------------------------------------------------------
__global__ __launch_bounds__(256, 4) void quad_h(
    const float* __restrict__ S, const __bf16* __restrict__ Szb,
    const float* __restrict__ prev, const float* __restrict__ zb,
    const float* __restrict__ hb, const float* __restrict__ ghb,
    const float* __restrict__ wh_s, const float* __restrict__ uh_s,
    const __bf16* __restrict__ Fw_h, const __bf16* __restrict__ G,
    const float* __restrict__ scal, float* __restrict__ out_sig)
{
  const int bid = blockIdx.x;
  const int s = bid >> 6, b = bid & 63;
  const size_t sb = (size_t)b * MATN;
  const int t = threadIdx.x, w = t >> 6, l = t & 63, r = l & 15, q = l >> 4;
  const __bf16* Gb = G + sb;

  __shared__ __align__(16) __bf16 Th[16*PITCH];

  f32x4 ah[4] = {};
#pragma unroll
  for (int kt = 0; kt < 8; ++kt) {
    const bf16x8 af = frag_load(Fw_h, s, kt, l);
#pragma unroll
    for (int ct = 0; ct < 4; ++ct) {
      const bf16x8 bv = frag_load(Gb, w*4 + ct, kt, l);
      ah[ct] = __builtin_amdgcn_mfma_f32_16x16x32_bf16(af, bv, ah[ct], 0, 0, 0);
    }
  }
#pragma unroll
  for (int ct = 0; ct < 4; ++ct)
#pragma unroll
    for (int v = 0; v < 4; ++v)
      Th[(q*4 + v)*PITCH + w*64 + ct*16 + r] = (__bf16)ah[ct][v];
  __syncthreads();

  f32x4 qh[4] = {};
#pragma unroll
  for (int kt = 0; kt < 8; ++kt) {
    const bf16x8 at = *(const bf16x8*)&Th[r*PITCH + kt*32 + q*8];
#pragma unroll
    for (int ct = 0; ct < 4; ++ct) {
      const bf16x8 bv = frag_load(Fw_h, w*4 + ct, kt, l);
      qh[ct] = __builtin_amdgcn_mfma_f32_16x16x32_bf16(at, bv, qh[ct], 0, 0, 0);
    }
  }

  const float xx = scal[b];
  const float dscal = scal[192 + b] + scal[256 + b];  // gg + trG
  const int ib = s*16 + q*4;

  const __bf16* szp = Szb + ((size_t)(b*16 + s)*256 + t)*16;
  __align__(16) __bf16 sz16[16];
  *(uint4*)&sz16[0] = *(const uint4*)szp;
  *(uint4*)&sz16[8] = *(const uint4*)(szp + 8);

  const f32x4 g4 = *(const f32x4*)(ghb + b*UDIM + ib);
  const f32x4 p4 = *(const f32x4*)(prev + b*UDIM + ib);
  const f32x4 z4 = *(const f32x4*)(zb + b*UDIM + ib);
  const f32x4 h4 = *(const f32x4*)(hb + b*UDIM + ib);

#pragma unroll
  for (int ct = 0; ct < 4; ++ct) {
    const int j = (w*4 + ct)*16 + r;
    const float gj = ghb[b*UDIM + j];
    const float pj = prev[b*UDIM + j];
    const float zj = zb[b*UDIM + j];
    const float hj = hb[b*UDIM + j];
#pragma unroll
    for (int v = 0; v < 4; ++v) {
      const int i = ib + v;
      float qv = qh[ct][v];
      if (i == j) qv += dscal*softplusf(wh_s[i]) + xx*softplusf(uh_s[i]);
      const float Sg = qv * g4[v] * gj;
      const float sv = S[sb + (size_t)i*UDIM + j];
      const float sz = (float)sz16[ct*4 + v];
      float val = sv*(sz + z4[v]*zj)
                + sz*(p4[v] - h4[v])*(pj - hj)
                + Sg*(sz + (1.f - z4[v])*(1.f - zj));
      if (!isfinite(val)) val = 0.f;
      if (i == j) val = fabsf(val);
      out_sig[sb + (size_t)i*UDIM + j] = val;
    }
  }
}

// ---------------------------------------------------------------------------
extern "C" void kernel_launch(void* const* d_in, const int* in_sizes, int n_in,
                              void* d_out, int out_size, void* d_ws, size_t ws_size,
                              hipStream_t stream) {
  const float* x    = (const float*)d_in[0];
  const float* prev = (const float*)d_in[1];
  const float* S    = (const float*)d_in[2];
  const float* Uz   = (const float*)d_in[3];
  const float* uz_s = (const float*)d_in[4];
  const float* Wz   = (const float*)d_in[5];
  const float* wz_s = (const float*)d_in[6];
  const float* Ur   = (const float*)d_in[7];
  const float* ur_s = (const float*)d_in[8];
  const float* Wr   = (const float*)d_in[9];
  const float* wr_s = (const float*)d_in[10];
  const float* Uh   = (const float*)d_in[11];
  const float* uh_s = (const float*)d_in[12];
  const float* Wh   = (const float*)d_in[13];
  const float* wh_s = (const float*)d_in[14];

  float* out_mu  = (float*)d_out;
  float* out_sig = out_mu + BATCH*UDIM;

  float* ws   = (float*)d_ws;
  float* zb   = ws;
  float* rb   = zb  + BATCH*UDIM;
  float* gzb  = rb  + BATCH*UDIM;
  float* grb  = gzb + BATCH*UDIM;
  float* gin  = grb + BATCH*UDIM;
  float* hb   = gin + BATCH*UDIM;
  float* ghb  = hb  + BATCH*UDIM;
  float* scal = ghb + BATCH*UDIM;            // 512 floats
  __bf16* bws  = (__bf16*)(scal + 512);
  __bf16* Fu_z = bws;
  __bf16* Fw_z = Fu_z + MATN;
  __bf16* Fu_r = Fw_z + MATN;
  __bf16* Fw_r = Fu_r + MATN;
  __bf16* Fu_h = Fw_r + MATN;
  __bf16* Fw_h = Fu_h + MATN;
  const size_t BIG = (size_t)BATCH * MATN;
  __bf16* Szb = Fw_h + MATN;                 // [B,16,256,16] bf16 C-linear
  __bf16* G   = Szb + BIG;                   // [B,U,U] bf16 fragment-direct
  __bf16* Sf  = G + BIG;                     // [B,U,U] bf16 fragment-direct

  hipMemsetAsync(scal, 0, 512*sizeof(float), stream);

  prep_w<<<dim3(112), 256, 0, stream>>>(Uz, Wz, Ur, Wr, Uh, Wh,
      Fu_z, Fw_z, Fu_r, Fw_r, Fu_h, Fw_h, S, x, prev, scal);
  sconv_gates<<<dim3(1032), 256, 0, stream>>>(S, Sf, x, prev,
      Fu_z, Fw_z, Fu_r, Fw_r, zb, rb, gzb, grb, gin, scal);
  quad_zr_gh<<<dim3(1028), 256, 0, stream>>>(S, Sf, prev, rb, gzb, grb,
      wz_s, uz_s, wr_s, ur_s, Fw_z, Fw_r, scal, Szb, G,
      x, gin, zb, Fu_h, Fw_h, hb, ghb, out_mu);
  quad_h<<<dim3(1024), 256, 0, stream>>>(S, Szb, prev, zb, hb, ghb,
      wh_s, uh_s, Fw_h, G, scal, out_sig);
}

// Round 11
// 168.035 us; speedup vs baseline: 1.1776x; 1.0188x over previous
//
#include <hip/hip_runtime.h>
#include <math.h>

#define UDIM 256
#define BATCH 64
#define MATN 65536   // 256*256
#define PITCH 280    // LDS row pitch (bf16): 560B = 16B-aligned

typedef __bf16 bf16x8 __attribute__((ext_vector_type(8)));
typedef float  f32x4  __attribute__((ext_vector_type(4)));

__device__ __forceinline__ float softplusf(float x) { return log1pf(expf(x)); }
__device__ __forceinline__ float sigmoidf_(float x) { return 1.f/(1.f+expf(-x)); }

// Fragment-direct layout (verified rounds 4-10): chunk(rt,kt) = rows rt*16..+15
// x k kt*32..+31; lane = (row&15) | ((k>>3)&3)<<4; 8 contiguous bf16 per lane.
__device__ __forceinline__ bf16x8 frag_load(const __bf16* base, int rt, int kt, int lane) {
  return *(const bf16x8*)(base + (((size_t)(rt*8 + kt))*64 + lane)*8);
}

__device__ __forceinline__ bf16x8 cvt8(const float* p) {
  const float4 f0 = *(const float4*)p;
  const float4 f1 = *(const float4*)(p + 4);
  bf16x8 v;
  v[0]=(__bf16)f0.x; v[1]=(__bf16)f0.y; v[2]=(__bf16)f0.z; v[3]=(__bf16)f0.w;
  v[4]=(__bf16)f1.x; v[5]=(__bf16)f1.y; v[6]=(__bf16)f1.z; v[7]=(__bf16)f1.w;
  return v;
}

// ---------------------------------------------------------------------------
// prep_w (verified round 10): u<96 weight transposes; u>=96 scalars.
// scal: xx[0..63], pp[64..127], trS[128..191], gg[192..255], trG[256..319]
// ---------------------------------------------------------------------------
__global__ __launch_bounds__(256) void prep_w(
    const float* __restrict__ Uz, const float* __restrict__ Wz,
    const float* __restrict__ Ur, const float* __restrict__ Wr,
    const float* __restrict__ Uh, const float* __restrict__ Wh,
    __bf16* __restrict__ Fu_z, __bf16* __restrict__ Fw_z,
    __bf16* __restrict__ Fu_r, __bf16* __restrict__ Fw_r,
    __bf16* __restrict__ Fu_h, __bf16* __restrict__ Fw_h,
    const float* __restrict__ S, const float* __restrict__ x,
    const float* __restrict__ prev, float* __restrict__ scal)
{
  const int u = blockIdx.x;
  const int t = threadIdx.x;
  if (u >= 96) {
    const int blk = u - 96;
    const int b = blk*4 + (t >> 6), l = t & 63;
    const float4 xv = *(const float4*)(x + b*UDIM + l*4);
    float s0 = xv.x*xv.x + xv.y*xv.y + xv.z*xv.z + xv.w*xv.w;
    const float4 pv = *(const float4*)(prev + b*UDIM + l*4);
    float s1 = pv.x*pv.x + pv.y*pv.y + pv.z*pv.z + pv.w*pv.w;
    float s2 = 0.f;
#pragma unroll
    for (int e = 0; e < 4; ++e)
      s2 += S[(size_t)b*MATN + (size_t)(l*4 + e)*257];
    for (int off = 32; off; off >>= 1) {
      s0 += __shfl_down(s0, off);
      s1 += __shfl_down(s1, off);
      s2 += __shfl_down(s2, off);
    }
    if (l == 0) {
      atomicAdd(&scal[b], s0);
      atomicAdd(&scal[64 + b], s1);
      atomicAdd(&scal[128 + b], s2);
    }
    return;
  }
  const int mat = u >> 4, tl = u & 15;
  const int n0 = (tl & 3)*64, k0 = (tl >> 2)*64;
  const float* W; __bf16* F;
  switch (mat) {
    case 0: W = Uz; F = Fu_z; break;  case 1: W = Wz; F = Fw_z; break;
    case 2: W = Ur; F = Fu_r; break;  case 3: W = Wr; F = Fw_r; break;
    case 4: W = Uh; F = Fu_h; break;  default: W = Wh; F = Fw_h; break;
  }
  __shared__ float tile[64][65];
  const int tx = t & 15, ty = t >> 4;
#pragma unroll
  for (int rr = 0; rr < 4; ++rr) {
    const int row = ty*4 + rr;
    const float4 f = *(const float4*)(W + (size_t)(k0 + row)*UDIM + n0 + tx*4);
    tile[row][tx*4+0] = f.x; tile[row][tx*4+1] = f.y;
    tile[row][tx*4+2] = f.z; tile[row][tx*4+3] = f.w;
  }
  __syncthreads();
#pragma unroll
  for (int ss = 0; ss < 2; ++ss) {
    const int s = t + ss*256;
    const int rt_l = s >> 7, kt_l = (s >> 6) & 1, lane = s & 63;
    const int nl = rt_l*16 + (lane & 15), kb = kt_l*32 + (lane >> 4)*8;
    __align__(16) __bf16 tmp[8];
#pragma unroll
    for (int e = 0; e < 8; ++e) tmp[e] = (__bf16)tile[kb + e][nl];
    *(uint4*)(F + (((size_t)((((n0 >> 4) + rt_l)*8) + (k0 >> 5) + kt_l))*64 + lane)*8)
        = *(const uint4*)tmp;
  }
}

// ---------------------------------------------------------------------------
// sconv_gates (verified round 10): bid<8 gates_zr first; bid>=8 S -> Sf.
// ---------------------------------------------------------------------------
__global__ __launch_bounds__(256) void sconv_gates(
    const float* __restrict__ S, __bf16* __restrict__ Sf,
    const float* __restrict__ x, const float* __restrict__ prev,
    const __bf16* __restrict__ Fu_z, const __bf16* __restrict__ Fw_z,
    const __bf16* __restrict__ Fu_r, const __bf16* __restrict__ Fw_r,
    float* __restrict__ zb, float* __restrict__ rb,
    float* __restrict__ gzb, float* __restrict__ grb,
    float* __restrict__ gin, float* __restrict__ scal)
{
  const int bid = blockIdx.x;
  const int t = threadIdx.x, w = t >> 6, l = t & 63, r = l & 15, q = l >> 4;

  if (bid < 8) {
    const int jt = bid & 3, gate = bid >> 2;
    const __bf16* FU = gate ? Fu_r : Fu_z;
    const __bf16* FW = gate ? Fw_r : Fw_z;
    const int mrow = w*16 + r;
    f32x4 acc[4] = {};
#pragma unroll
    for (int ks = 0; ks < 16; ++ks) {
      const int k0 = ks*32;
      const float* asrc; const __bf16* B; int kk;
      if (k0 < 256) { asrc = x    + (size_t)mrow*UDIM + k0         + q*8; B = FU; kk = k0; }
      else          { asrc = prev + (size_t)mrow*UDIM + (k0 - 256) + q*8; B = FW; kk = k0 - 256; }
      const bf16x8 af = cvt8(asrc);
#pragma unroll
      for (int ni = 0; ni < 4; ++ni) {
        const bf16x8 bv = frag_load(B, jt*4 + ni, kk >> 5, l);
        acc[ni] = __builtin_amdgcn_mfma_f32_16x16x32_bf16(af, bv, acc[ni], 0, 0, 0);
      }
    }
    if (gate == 0) {
#pragma unroll
      for (int ni = 0; ni < 4; ++ni) {
        const int n = jt*64 + ni*16 + r;
#pragma unroll
        for (int v = 0; v < 4; ++v) {
          const int m = w*16 + q*4 + v;
          const float zv = sigmoidf_(acc[ni][v]);
          zb[m*UDIM + n]  = zv;
          gzb[m*UDIM + n] = zv * (1.f - zv);
        }
      }
    } else {
      float ggp[4] = {0.f, 0.f, 0.f, 0.f};
#pragma unroll
      for (int ni = 0; ni < 4; ++ni) {
        const int n = jt*64 + ni*16 + r;
#pragma unroll
        for (int v = 0; v < 4; ++v) {
          const int m = w*16 + q*4 + v;
          const float rv = sigmoidf_(acc[ni][v]);
          const float pv = prev[m*UDIM + n];
          const float g2 = pv * rv;
          rb[m*UDIM + n]  = rv;
          grb[m*UDIM + n] = rv * (1.f - rv);
          gin[m*UDIM + n] = g2;
          ggp[v] += g2 * g2;
        }
      }
#pragma unroll
      for (int s = 1; s < 16; s <<= 1)
#pragma unroll
        for (int v = 0; v < 4; ++v) ggp[v] += __shfl_xor(ggp[v], s);
      if (r == 0)
#pragma unroll
        for (int v = 0; v < 4; ++v)
          atomicAdd(&scal[192 + w*16 + q*4 + v], ggp[v]);
    }
    return;
  }

  const int u = bid - 8;
  const int bx = u & 3, by = (u >> 2) & 3, b = u >> 4;
  const size_t sb = (size_t)b * MATN;
#pragma unroll
  for (int ss = 0; ss < 2; ++ss) {
    const int s = t + ss*256;
    const int chunk = s >> 6, lane = s & 63;
    const int rt_l = chunk >> 1, kt_l = chunk & 1;
    const int row = by*64 + rt_l*16 + (lane & 15);
    const int col = bx*64 + kt_l*32 + (lane >> 4)*8;
    const bf16x8 v = cvt8(S + sb + (size_t)row*UDIM + col);
    *(bf16x8*)(Sf + sb + (((size_t)((by*4 + rt_l)*8 + bx*2 + kt_l))*64 + lane)*8) = v;
  }
}

// ---------------------------------------------------------------------------
// quad_zr_gh: grid 2052.
//   bid<4: gates_h rider (dispatched first).
//   bid>=4: GATE-SPLIT quad block — one 16-row strip, ONE gate:
//     id = bid-4; id<1024 -> r gate (heavier epilogue, starts first),
//     id>=1024 -> z gate.  s = (id>>6)&15, b = id&63 (XCD affinity kept).
//     left T = Wt_g[strip] @ S_b (Sf frag-direct) -> LDS; right Q = T @ W_g;
//     z: -> Szb (C-linear bf16); r: sigma_g -> G (frag-direct) + trG.
// ---------------------------------------------------------------------------
__global__ __launch_bounds__(256, 4) void quad_zr_gh(
    const float* __restrict__ S, const __bf16* __restrict__ Sf,
    const float* __restrict__ prev,
    const float* __restrict__ rb, const float* __restrict__ gzb,
    const float* __restrict__ grb,
    const float* __restrict__ wz_s, const float* __restrict__ uz_s,
    const float* __restrict__ wr_s, const float* __restrict__ ur_s,
    const __bf16* __restrict__ Fw_z, const __bf16* __restrict__ Fw_r,
    float* __restrict__ scal, __bf16* __restrict__ Szb, __bf16* __restrict__ G,
    const float* __restrict__ x, const float* __restrict__ gin,
    const float* __restrict__ zb,
    const __bf16* __restrict__ Fu_h, const __bf16* __restrict__ Fw_h,
    float* __restrict__ hb, float* __restrict__ ghb, float* __restrict__ mu_out)
{
  const int bid = blockIdx.x;
  const int t = threadIdx.x, w = t >> 6, l = t & 63, r = l & 15, q = l >> 4;

  if (bid < 4) {
    // ---- gates_h (verified rounds 5-10) ----
    const int jt = bid;
    const int mrow = w*16 + r;
    f32x4 acc[4] = {};
#pragma unroll
    for (int ks = 0; ks < 16; ++ks) {
      const int k0 = ks*32;
      const float* asrc; const __bf16* B; int kk;
      if (k0 < 256) { asrc = x   + (size_t)mrow*UDIM + k0         + q*8; B = Fu_h; kk = k0; }
      else          { asrc = gin + (size_t)mrow*UDIM + (k0 - 256) + q*8; B = Fw_h; kk = k0 - 256; }
      const bf16x8 af = cvt8(asrc);
#pragma unroll
      for (int ni = 0; ni < 4; ++ni) {
        const bf16x8 bv = frag_load(B, jt*4 + ni, kk >> 5, l);
        acc[ni] = __builtin_amdgcn_mfma_f32_16x16x32_bf16(af, bv, acc[ni], 0, 0, 0);
      }
    }
#pragma unroll
    for (int ni = 0; ni < 4; ++ni) {
      const int n = jt*64 + ni*16 + r;
#pragma unroll
      for (int v = 0; v < 4; ++v) {
        const int m = w*16 + q*4 + v;
        const float hv = tanhf(acc[ni][v]);
        const float zv = zb[m*UDIM + n];
        hb[m*UDIM + n]  = hv;
        ghb[m*UDIM + n] = 1.f - hv*hv;
        mu_out[m*UDIM + n] = zv * prev[m*UDIM + n] + (1.f - zv) * hv;
      }
    }
    return;
  }

  const int id = bid - 4;
  const int gater = (id < 1024);            // first half = r gate
  const int rem = id & 1023;
  const int s = rem >> 6, b = rem & 63;     // strip 0..15, batch 0..63
  const size_t sb = (size_t)b * MATN;
  const __bf16* Sfb = Sf + sb;
  const __bf16* FW = gater ? Fw_r : Fw_z;

  __shared__ __align__(16) __bf16 T[16*PITCH];

  // ---- left GEMM: T strip ----
  f32x4 a[4] = {};
#pragma unroll
  for (int kt = 0; kt < 8; ++kt) {
    const bf16x8 af = frag_load(FW, s, kt, l);
#pragma unroll
    for (int ct = 0; ct < 4; ++ct) {
      const bf16x8 bv = frag_load(Sfb, w*4 + ct, kt, l);
      a[ct] = __builtin_amdgcn_mfma_f32_16x16x32_bf16(af, bv, a[ct], 0, 0, 0);
    }
  }
#pragma unroll
  for (int ct = 0; ct < 4; ++ct)
#pragma unroll
    for (int v = 0; v < 4; ++v)
      T[(q*4 + v)*PITCH + w*64 + ct*16 + r] = (__bf16)a[ct][v];
  __syncthreads();

  // ---- right GEMM from LDS ----
  f32x4 qx[4] = {};
#pragma unroll
  for (int kt = 0; kt < 8; ++kt) {
    const bf16x8 at = *(const bf16x8*)&T[r*PITCH + kt*32 + q*8];
#pragma unroll
    for (int ct = 0; ct < 4; ++ct) {
      const bf16x8 bw = frag_load(FW, w*4 + ct, kt, l);
      qx[ct] = __builtin_amdgcn_mfma_f32_16x16x32_bf16(at, bw, qx[ct], 0, 0, 0);
    }
  }

  const float xx = scal[b];
  const float dscal = scal[64 + b] + scal[128 + b];   // pp + trS
  const int ib = s*16 + q*4;

  if (!gater) {
    // ---- z epilogue -> Szb (C-linear bf16) ----
    const f32x4 g4 = *(const f32x4*)(gzb + b*UDIM + ib);
    __align__(16) __bf16 o16[16];
#pragma unroll
    for (int ct = 0; ct < 4; ++ct) {
      const int j = (w*4 + ct)*16 + r;
      const float gj = gzb[b*UDIM + j];
#pragma unroll
      for (int v = 0; v < 4; ++v) {
        const int i = ib + v;
        float qv = qx[ct][v];
        if (i == j) qv += dscal*softplusf(wz_s[i]) + xx*softplusf(uz_s[i]);
        o16[ct*4 + v] = (__bf16)(qv * g4[v] * gj);
      }
    }
    __bf16* dst = Szb + ((size_t)(b*16 + s)*256 + t)*16;
    *(uint4*)dst       = *(const uint4*)&o16[0];
    *(uint4*)(dst + 8) = *(const uint4*)&o16[8];
  } else {
    // ---- r epilogue -> sigma_g + trG ----
    float gvals[16];
    float trg = 0.f;
    {
      const f32x4 g4 = *(const f32x4*)(grb + b*UDIM + ib);
      const f32x4 p4 = *(const f32x4*)(prev + b*UDIM + ib);
      const f32x4 r4 = *(const f32x4*)(rb + b*UDIM + ib);
#pragma unroll
      for (int ct = 0; ct < 4; ++ct) {
        const int j = (w*4 + ct)*16 + r;
        const float gj = grb[b*UDIM + j];
        const float pj = prev[b*UDIM + j];
        const float rj = rb[b*UDIM + j];
#pragma unroll
        for (int v = 0; v < 4; ++v) {
          const int i = ib + v;
          float qv = qx[ct][v];
          if (i == j) qv += dscal*softplusf(wr_s[i]) + xx*softplusf(ur_s[i]);
          const float Sg = qv * g4[v] * gj;
          const float sv = S[sb + (size_t)i*UDIM + j];
          const float go = Sg*(sv + p4[v]*pj) + r4[v]*rj*sv;
          gvals[ct*4 + v] = go;
          if (i == j) trg += go;
        }
      }
    }
    if (trg != 0.f) atomicAdd(&scal[256 + b], trg);

    // ---- bounce sigma_g strip -> fragment-direct G (reuse T) ----
    __syncthreads();
#pragma unroll
    for (int ct = 0; ct < 4; ++ct)
#pragma unroll
      for (int v = 0; v < 4; ++v)
        T[(q*4 + v)*PITCH + w*64 + ct*16 + r] = (__bf16)gvals[ct*4 + v];
    __syncthreads();
#pragma unroll
    for (int ee = 0; ee < 2; ++ee) {
      const int e = t + ee*256;
      const int kt = e >> 6, le = e & 63;
      const uint4 vv = *(const uint4*)&T[(le & 15)*PITCH + kt*32 + (le >> 4)*8];
      *(uint4*)(G + sb + (((size_t)(s*8 + kt))*64 + le)*8) = vv;
    }
  }
}

// ---------------------------------------------------------------------------
// quad_h (EXACT round-8/10 version): one 16-row strip of one batch.
// ---------------------------------------------------------------------------
__global__ __launch_bounds__(256, 4) void quad_h(
    const float* __restrict__ S, const __bf16* __restrict__ Szb,
    const float* __restrict__ prev, const float* __restrict__ zb,
    const float* __restrict__ hb, const float* __restrict__ ghb,
    const float* __restrict__ wh_s, const float* __restrict__ uh_s,
    const __bf16* __restrict__ Fw_h, const __bf16* __restrict__ G,
    const float* __restrict__ scal, float* __restrict__ out_sig)
{
  const int bid = blockIdx.x;
  const int s = bid >> 6, b = bid & 63;
  const size_t sb = (size_t)b * MATN;
  const int t = threadIdx.x, w = t >> 6, l = t & 63, r = l & 15, q = l >> 4;
  const __bf16* Gb = G + sb;

  __shared__ __align__(16) __bf16 Th[16*PITCH];

  f32x4 ah[4] = {};
#pragma unroll
  for (int kt = 0; kt < 8; ++kt) {
    const bf16x8 af = frag_load(Fw_h, s, kt, l);
#pragma unroll
    for (int ct = 0; ct < 4; ++ct) {
      const bf16x8 bv = frag_load(Gb, w*4 + ct, kt, l);
      ah[ct] = __builtin_amdgcn_mfma_f32_16x16x32_bf16(af, bv, ah[ct], 0, 0, 0);
    }
  }
#pragma unroll
  for (int ct = 0; ct < 4; ++ct)
#pragma unroll
    for (int v = 0; v < 4; ++v)
      Th[(q*4 + v)*PITCH + w*64 + ct*16 + r] = (__bf16)ah[ct][v];
  __syncthreads();

  f32x4 qh[4] = {};
#pragma unroll
  for (int kt = 0; kt < 8; ++kt) {
    const bf16x8 at = *(const bf16x8*)&Th[r*PITCH + kt*32 + q*8];
#pragma unroll
    for (int ct = 0; ct < 4; ++ct) {
      const bf16x8 bv = frag_load(Fw_h, w*4 + ct, kt, l);
      qh[ct] = __builtin_amdgcn_mfma_f32_16x16x32_bf16(at, bv, qh[ct], 0, 0, 0);
    }
  }

  const float xx = scal[b];
  const float dscal = scal[192 + b] + scal[256 + b];  // gg + trG
  const int ib = s*16 + q*4;

  const __bf16* szp = Szb + ((size_t)(b*16 + s)*256 + t)*16;
  __align__(16) __bf16 sz16[16];
  *(uint4*)&sz16[0] = *(const uint4*)szp;
  *(uint4*)&sz16[8] = *(const uint4*)(szp + 8);

  const f32x4 g4 = *(const f32x4*)(ghb + b*UDIM + ib);
  const f32x4 p4 = *(const f32x4*)(prev + b*UDIM + ib);
  const f32x4 z4 = *(const f32x4*)(zb + b*UDIM + ib);
  const f32x4 h4 = *(const f32x4*)(hb + b*UDIM + ib);

#pragma unroll
  for (int ct = 0; ct < 4; ++ct) {
    const int j = (w*4 + ct)*16 + r;
    const float gj = ghb[b*UDIM + j];
    const float pj = prev[b*UDIM + j];
    const float zj = zb[b*UDIM + j];
    const float hj = hb[b*UDIM + j];
#pragma unroll
    for (int v = 0; v < 4; ++v) {
      const int i = ib + v;
      float qv = qh[ct][v];
      if (i == j) qv += dscal*softplusf(wh_s[i]) + xx*softplusf(uh_s[i]);
      const float Sg = qv * g4[v] * gj;
      const float sv = S[sb + (size_t)i*UDIM + j];
      const float sz = (float)sz16[ct*4 + v];
      float val = sv*(sz + z4[v]*zj)
                + sz*(p4[v] - h4[v])*(pj - hj)
                + Sg*(sz + (1.f - z4[v])*(1.f - zj));
      if (!isfinite(val)) val = 0.f;
      if (i == j) val = fabsf(val);
      out_sig[sb + (size_t)i*UDIM + j] = val;
    }
  }
}

// ---------------------------------------------------------------------------
extern "C" void kernel_launch(void* const* d_in, const int* in_sizes, int n_in,
                              void* d_out, int out_size, void* d_ws, size_t ws_size,
                              hipStream_t stream) {
  const float* x    = (const float*)d_in[0];
  const float* prev = (const float*)d_in[1];
  const float* S    = (const float*)d_in[2];
  const float* Uz   = (const float*)d_in[3];
  const float* uz_s = (const float*)d_in[4];
  const float* Wz   = (const float*)d_in[5];
  const float* wz_s = (const float*)d_in[6];
  const float* Ur   = (const float*)d_in[7];
  const float* ur_s = (const float*)d_in[8];
  const float* Wr   = (const float*)d_in[9];
  const float* wr_s = (const float*)d_in[10];
  const float* Uh   = (const float*)d_in[11];
  const float* uh_s = (const float*)d_in[12];
  const float* Wh   = (const float*)d_in[13];
  const float* wh_s = (const float*)d_in[14];

  float* out_mu  = (float*)d_out;
  float* out_sig = out_mu + BATCH*UDIM;

  float* ws   = (float*)d_ws;
  float* zb   = ws;
  float* rb   = zb  + BATCH*UDIM;
  float* gzb  = rb  + BATCH*UDIM;
  float* grb  = gzb + BATCH*UDIM;
  float* gin  = grb + BATCH*UDIM;
  float* hb   = gin + BATCH*UDIM;
  float* ghb  = hb  + BATCH*UDIM;
  float* scal = ghb + BATCH*UDIM;            // 512 floats
  __bf16* bws  = (__bf16*)(scal + 512);
  __bf16* Fu_z = bws;
  __bf16* Fw_z = Fu_z + MATN;
  __bf16* Fu_r = Fw_z + MATN;
  __bf16* Fw_r = Fu_r + MATN;
  __bf16* Fu_h = Fw_r + MATN;
  __bf16* Fw_h = Fu_h + MATN;
  const size_t BIG = (size_t)BATCH * MATN;
  __bf16* Szb = Fw_h + MATN;                 // [B,16,256,16] bf16 C-linear
  __bf16* G   = Szb + BIG;                   // [B,U,U] bf16 fragment-direct
  __bf16* Sf  = G + BIG;                     // [B,U,U] bf16 fragment-direct

  hipMemsetAsync(scal, 0, 512*sizeof(float), stream);

  prep_w<<<dim3(112), 256, 0, stream>>>(Uz, Wz, Ur, Wr, Uh, Wh,
      Fu_z, Fw_z, Fu_r, Fw_r, Fu_h, Fw_h, S, x, prev, scal);
  sconv_gates<<<dim3(1032), 256, 0, stream>>>(S, Sf, x, prev,
      Fu_z, Fw_z, Fu_r, Fw_r, zb, rb, gzb, grb, gin, scal);
  quad_zr_gh<<<dim3(2052), 256, 0, stream>>>(S, Sf, prev, rb, gzb, grb,
      wz_s, uz_s, wr_s, ur_s, Fw_z, Fw_r, scal, Szb, G,
      x, gin, zb, Fu_h, Fw_h, hb, ghb, out_mu);
  quad_h<<<dim3(1024), 256, 0, stream>>>(S, Szb, prev, zb, hb, ghb,
      wh_s, uh_s, Fw_h, G, scal, out_sig);
}